// Round 5
// baseline (1769.407 us; speedup 1.0000x reference)
//
#include <hip/hip_runtime.h>
#include <math.h>

#define NB 16
#define NR 64
#define NCOL 64
#define ND 2048
#define DIM 512

typedef __attribute__((ext_vector_type(4))) float f32x4;
typedef __attribute__((ext_vector_type(8))) short bf16x8;
typedef __attribute__((ext_vector_type(8))) unsigned short us8;

// ---------------- workspace layout (float offsets) ----------------
#define OFF_RHNUM  0L
#define OFF_CHNUM  1024L
#define OFF_DCNUM  2048L
#define OFF_RHW    34816L
#define OFF_CHW    35840L
#define OFF_QROW   36864L
#define OFF_QCOL   45056L
#define OFF_PRER   53248L
#define OFF_PREC   577536L
#define OFF_INFORC 1101824L   // ihiT/iloT bf16 info planes [b][512][128] (4 MB)
#define OFF_BITS   2150400L
#define OFF_DCS    4247552L   // dhi/dlo row-major planes
#define OFF_PROJ   21024768L  // thi/tlo transposed dcs planes, then phi/plo proj planes
#define WS_FLOATS  37801984L  // 151.2 MB
// whi/wlo live in the out-dc slice (dead mid-iteration)

// RNE fp32 -> bf16 split: v ~= hi + lo, both bf16
__device__ inline void bsplit(float v, unsigned short& h, unsigned short& l) {
    unsigned uv = __float_as_uint(v);
    unsigned hb = (uv + 0x7FFFu + ((uv >> 16) & 1u)) >> 16;
    h = (unsigned short)hb;
    float lo = v - __uint_as_float(hb << 16);
    unsigned lv = __float_as_uint(lo);
    l = (unsigned short)((lv + 0x7FFFu + ((lv >> 16) & 1u)) >> 16);
}

// spread 8 bits to every 4th position of a 32-bit word
__device__ inline unsigned spread4(unsigned x) {
    x = (x | (x << 12)) & 0x000F000Fu;
    x = (x | (x << 6))  & 0x03030303u;
    x = (x | (x << 3))  & 0x11111111u;
    return x;
}

// shared MFMA phase: 2 ks x (4x4) x 2 products (A exact, B hi+lo)
__device__ inline void mfma_phase2(const unsigned short* Aexp, const unsigned short* Bhi,
                                   const unsigned short* Blo, int wm, int wn, int lane,
                                   f32x4 acc[4][4])
{
    #pragma unroll
    for (int ks = 0; ks < 2; ks++) {
        bf16x8 af[4], bh[4], bl[4];
        #pragma unroll
        for (int i = 0; i < 4; i++) {
            int rr = wm * 64 + i * 16 + (lane & 15);
            int cc = (ks * 4 + (lane >> 4)) ^ (rr & 7);
            af[i] = *(const bf16x8*)((const char*)Aexp + rr * 128 + cc * 16);
            int nn = wn * 64 + i * 16 + (lane & 15);
            int c2 = (ks * 4 + (lane >> 4)) ^ (nn & 7);
            bh[i] = *(const bf16x8*)((const char*)Bhi + nn * 128 + c2 * 16);
            bl[i] = *(const bf16x8*)((const char*)Blo + nn * 128 + c2 * 16);
        }
        #pragma unroll
        for (int mi = 0; mi < 4; mi++)
            #pragma unroll
            for (int ni = 0; ni < 4; ni++) {
                acc[mi][ni] = __builtin_amdgcn_mfma_f32_16x16x32_bf16(af[mi], bh[ni], acc[mi][ni], 0, 0, 0);
                acc[mi][ni] = __builtin_amdgcn_mfma_f32_16x16x32_bf16(af[mi], bl[ni], acc[mi][ni], 0, 0, 0);
            }
    }
}

// ============ gate for rh/ch rows ============
__global__ __launch_bounds__(256) void k_gate_rc(
    const float* __restrict__ rh, const float* __restrict__ ch,
    const int* __restrict__ rm, const int* __restrict__ cm,
    const float* __restrict__ wnode,
    float* __restrict__ rh_w, float* __restrict__ ch_w)
{
    int wave = threadIdx.x >> 6, lane = threadIdx.x & 63;
    int idx = blockIdx.x * 4 + wave;   // < 2048
    const float* xrow; float* outw; int mval;
    if (idx < NB * NR) {
        int b = idx >> 6, r = idx & 63;
        xrow = rh + ((long)b * NR + r) * DIM; mval = rm[b * NR + r]; outw = rh_w + b * NR + r;
    } else {
        int tt = idx - NB * NR; int b = tt >> 6, c = tt & 63;
        xrow = ch + ((long)b * NCOL + c) * DIM; mval = cm[b * NCOL + c]; outw = ch_w + b * NCOL + c;
    }
    const float4* px = (const float4*)xrow;
    const float4* pw = (const float4*)wnode;
    float4 xa = px[lane * 2], xb = px[lane * 2 + 1];
    float4 wa = pw[lane * 2], wb = pw[lane * 2 + 1];
    float s = xa.x * wa.x + xa.y * wa.y + xa.z * wa.z + xa.w * wa.w
            + xb.x * wb.x + xb.y * wb.y + xb.z * wb.z + xb.w * wb.w;
    #pragma unroll
    for (int o = 32; o > 0; o >>= 1) s += __shfl_xor(s, o, 64);
    if (lane == 0) {
        float g = 1.f / (1.f + expf(-s));
        *outw = mval ? g : 0.f;
    }
}

// ============ gate+split dc -> dhi/dlo [b][2048][512] AND thi/tlo [b][512][2048] ============
__global__ __launch_bounds__(256) void k_split(
    const float* __restrict__ src, const float* __restrict__ wnode, const int* __restrict__ dmask,
    unsigned short* __restrict__ dhi, unsigned short* __restrict__ dlo,
    unsigned short* __restrict__ thi, unsigned short* __restrict__ tlo)
{
    int b = blockIdx.y, j0 = blockIdx.x * 16;
    __shared__ float X[16 * 512];
    __shared__ float scs[16];
    int t = threadIdx.x;
    int r = t >> 4, u = t & 15;
    const float* row = src + ((long)b * ND + j0 + r) * DIM;
    float part = 0.f;
    #pragma unroll
    for (int i = 0; i < 8; i++) {
        int col = i * 64 + u * 4;
        float4 v = *(const float4*)(row + col);
        float4 w = *(const float4*)(wnode + col);
        part += v.x * w.x + v.y * w.y + v.z * w.z + v.w * w.w;
        *(float4*)&X[r * 512 + (col ^ ((r & 7) * 4))] = v;
    }
    part += __shfl_xor(part, 1, 64);
    part += __shfl_xor(part, 2, 64);
    part += __shfl_xor(part, 4, 64);
    part += __shfl_xor(part, 8, 64);
    if (u == 0) {
        float g = 1.f / (1.f + expf(-part));
        scs[r] = (dmask[(long)b * ND + j0 + r] != 0) ? g : 0.f;
    }
    __syncthreads();
    // row-major planes
    {
        float s = scs[r];
        long ob = ((long)b * ND + j0 + r) * DIM + u * 32;
        #pragma unroll
        for (int g = 0; g < 4; g++) {
            us8 ph, pl;
            #pragma unroll
            for (int e = 0; e < 8; e++) {
                int cc = u * 32 + g * 8 + e;
                float v = X[r * 512 + (cc ^ ((r & 7) * 4))] * s;
                unsigned short hh, ll; bsplit(v, hh, ll);
                ph[e] = hh; pl[e] = ll;
            }
            *(us8*)(dhi + ob + g * 8) = ph;
            *(us8*)(dlo + ob + g * 8) = pl;
        }
    }
    // transposed planes
    #pragma unroll
    for (int h = 0; h < 2; h++) {
        int n = t + h * 256;
        us8 ph0, ph1, pl0, pl1;
        #pragma unroll
        for (int rr = 0; rr < 16; rr++) {
            float v = X[rr * 512 + (n ^ ((rr & 7) * 4))] * scs[rr];
            unsigned short hh, ll; bsplit(v, hh, ll);
            if (rr < 8) { ph0[rr] = hh; pl0[rr] = ll; }
            else        { ph1[rr - 8] = hh; pl1[rr - 8] = ll; }
        }
        long ob = ((long)b * DIM + n) * ND + j0;
        *(us8*)(thi + ob) = ph0; *(us8*)(thi + ob + 8) = ph1;
        *(us8*)(tlo + ob) = pl0; *(us8*)(tlo + ob + 8) = pl1;
    }
}

// ============ split w_sr -> whi/wlo bf16 [512][512] ============
__global__ __launch_bounds__(256) void k_wsplit(
    const float* __restrict__ w, unsigned short* __restrict__ whi, unsigned short* __restrict__ wlo)
{
    long i = ((long)blockIdx.x * 256 + threadIdx.x) * 8;
    float4 a = *(const float4*)(w + i), b4 = *(const float4*)(w + i + 4);
    float v[8] = {a.x, a.y, a.z, a.w, b4.x, b4.y, b4.z, b4.w};
    us8 ph, pl;
    #pragma unroll
    for (int t = 0; t < 8; t++) {
        unsigned short hh, ll; bsplit(v[t], hh, ll);
        ph[t] = hh; pl[t] = ll;
    }
    *(us8*)(whi + i) = ph;
    *(us8*)(wlo + i) = pl;
}

// ============ q projections (once) ============
__global__ __launch_bounds__(256) void k_q(
    const float* __restrict__ q, const float* __restrict__ wrq, const float* __restrict__ wcq,
    float* __restrict__ qrow, float* __restrict__ qcol)
{
    int b = blockIdx.z;
    const float* W = blockIdx.y ? wcq : wrq;
    float* out = blockIdx.y ? qcol : qrow;
    int wave = threadIdx.x >> 6, lane = threadIdx.x & 63;
    int n = blockIdx.x * 4 + wave;
    const float4* qp = (const float4*)(q + (long)b * DIM);
    const float4* wp = (const float4*)(W + (long)n * DIM);
    float4 a0 = qp[lane * 2], a1 = qp[lane * 2 + 1];
    float4 w0 = wp[lane * 2], w1 = wp[lane * 2 + 1];
    float s = a0.x * w0.x + a0.y * w0.y + a0.z * w0.z + a0.w * w0.w
            + a1.x * w1.x + a1.y * w1.y + a1.z * w1.z + a1.w * w1.w;
    #pragma unroll
    for (int o = 32; o > 0; o >>= 1) s += __shfl_xor(s, o, 64);
    if (lane == 0) out[(long)b * DIM + n] = s;
}

// ============ pack same_row bits (vectorized) + partial dc_num ============
__global__ __launch_bounds__(256) void k_bits(
    const int* __restrict__ sr, const int* __restrict__ sc, const int* __restrict__ dmask,
    unsigned* __restrict__ bits, float* __restrict__ dcnum)
{
    long bi = blockIdx.x;                    // = b*ND + i
    int b = (int)(bi >> 11);
    int dmi = dmask[bi];
    int wave = threadIdx.x >> 6, lane = threadIdx.x & 63;
    const int4* sr4 = (const int4*)(sr + bi * ND);
    const int4* sc4 = (const int4*)(sc + bi * ND);
    const int4* dm4 = (const int4*)(dmask + (long)b * ND);
    unsigned* brow = bits + bi * 64;
    int cnt = 0;
    #pragma unroll
    for (int h = 0; h < 2; h++) {
        int vidx = wave * 128 + h * 64 + lane;    // int4 index; j = 4*vidx+k
        int4 vs = sr4[vidx];
        int4 vc = sc4[vidx];
        int4 vd = dm4[vidx];
        bool d0 = dmi && vd.x, d1 = dmi && vd.y, d2 = dmi && vd.z, d3 = dmi && vd.w;
        unsigned long long m0 = __ballot(d0 && vs.x);
        unsigned long long m1 = __ballot(d1 && vs.y);
        unsigned long long m2 = __ballot(d2 && vs.z);
        unsigned long long m3 = __ballot(d3 && vs.w);
        unsigned long long n0 = __ballot(d0 && vc.x);
        unsigned long long n1 = __ballot(d1 && vc.y);
        unsigned long long n2 = __ballot(d2 && vc.z);
        unsigned long long n3 = __ballot(d3 && vc.w);
        cnt += __popcll(m0) + __popcll(m1) + __popcll(m2) + __popcll(m3)
             + __popcll(n0) + __popcll(n1) + __popcll(n2) + __popcll(n3);
        if (lane < 8) {
            unsigned w = spread4((unsigned)(m0 >> (8 * lane)) & 0xFFu)
                       | (spread4((unsigned)(m1 >> (8 * lane)) & 0xFFu) << 1)
                       | (spread4((unsigned)(m2 >> (8 * lane)) & 0xFFu) << 2)
                       | (spread4((unsigned)(m3 >> (8 * lane)) & 0xFFu) << 3);
            brow[wave * 16 + h * 8 + lane] = w;
        }
    }
    __shared__ int red[4];
    if (lane == 0) red[wave] = cnt;
    __syncthreads();
    if (threadIdx.x == 0) dcnum[bi] = (float)(red[0] + red[1] + red[2] + red[3]);
}

// ============ rh_num / ch_num ============
__global__ __launch_bounds__(256) void k_rcnum(
    const int* __restrict__ rel_rd, const int* __restrict__ rel_cd,
    const int* __restrict__ rm, const int* __restrict__ cm, const int* __restrict__ dmask,
    float* __restrict__ rh_num, float* __restrict__ ch_num)
{
    int wave = threadIdx.x >> 6, lane = threadIdx.x & 63;
    long idx = (long)blockIdx.x * 4 + wave;  // < 2048
    const int* row; int mval; float* out; const int* dmb;
    if (idx < NB * NR) {
        int b = (int)(idx >> 6), r = (int)(idx & 63);
        row = rel_rd + ((long)b * NR + r) * ND; mval = rm[b * NR + r];
        out = rh_num + b * NR + r; dmb = dmask + (long)b * ND;
    } else {
        long tt = idx - NB * NR; int b = (int)(tt >> 6), c = (int)(tt & 63);
        row = rel_cd + ((long)b * NCOL + c) * ND; mval = cm[b * NCOL + c];
        out = ch_num + b * NCOL + c; dmb = dmask + (long)b * ND;
    }
    int cnt = 0;
    for (int rr = 0; rr < 32; rr++) {
        int j = rr * 64 + lane;
        cnt += (row[j] != 0 && dmb[j] != 0) ? 1 : 0;
    }
    #pragma unroll
    for (int o = 32; o > 0; o >>= 1) cnt += __shfl_xor(cnt, o, 64);
    if (lane == 0) {
        float s = mval ? (float)cnt : 0.f;
        *out = (s >= 1.f) ? (s + 1.f) : 1.f;
    }
}

// ============ finalize dc_num ============
__global__ __launch_bounds__(256) void k_dcnum_final(
    const int* __restrict__ rel_rd, const int* __restrict__ rel_cd,
    const int* __restrict__ rm, const int* __restrict__ cm, const int* __restrict__ dmask,
    float* __restrict__ dcnum)
{
    int b = blockIdx.y;
    int j = blockIdx.x * 256 + threadIdx.x;
    const int* rd = rel_rd + (long)b * NR * ND;
    const int* cd = rel_cd + (long)b * NCOL * ND;
    const int* rmb = rm + b * NR;
    const int* cmb = cm + b * NCOL;
    int cnt = 0;
    for (int r = 0; r < NR; r++)  cnt += (rd[(long)r * ND + j] != 0 && rmb[r] != 0) ? 1 : 0;
    for (int c = 0; c < NCOL; c++) cnt += (cd[(long)c * ND + j] != 0 && cmb[c] != 0) ? 1 : 0;
    float add = (dmask[(long)b * ND + j] != 0) ? (float)cnt : 0.f;
    float tv = dcnum[(long)b * ND + j] + add;
    dcnum[(long)b * ND + j] = (tv >= 1.f) ? tv : 1.f;
}

// ============ gemm_info: M=64,N=512,K=512 -> transposed bf16 info planes [b][512][128] ============
__global__ __launch_bounds__(256) void gemm_info(
    const float* __restrict__ A, long sA,
    const float* __restrict__ W,
    unsigned short* __restrict__ ihiT, unsigned short* __restrict__ iloT, int hoff,
    const float* __restrict__ rowscale, float alpha)
{
    int b = blockIdx.z;
    int n0 = blockIdx.x * 64;
    __shared__ float As[32][68], Ws[32][68];
    float acc[4][4] = {};
    int tx = threadIdx.x & 15, ty = threadIdx.x >> 4;
    int lm = threadIdx.x >> 2, lk = (threadIdx.x & 3) * 8;
    const float* Ab = A + (long)b * sA;
    for (int k0 = 0; k0 < DIM; k0 += 32) {
        const float4* pa = (const float4*)(Ab + (long)lm * DIM + k0 + lk);
        float4 va0 = pa[0], va1 = pa[1];
        const float4* pw = (const float4*)(W + (long)(n0 + lm) * DIM + k0 + lk);
        float4 vw0 = pw[0], vw1 = pw[1];
        As[lk + 0][lm] = va0.x; As[lk + 1][lm] = va0.y; As[lk + 2][lm] = va0.z; As[lk + 3][lm] = va0.w;
        As[lk + 4][lm] = va1.x; As[lk + 5][lm] = va1.y; As[lk + 6][lm] = va1.z; As[lk + 7][lm] = va1.w;
        Ws[lk + 0][lm] = vw0.x; Ws[lk + 1][lm] = vw0.y; Ws[lk + 2][lm] = vw0.z; Ws[lk + 3][lm] = vw0.w;
        Ws[lk + 4][lm] = vw1.x; Ws[lk + 5][lm] = vw1.y; Ws[lk + 6][lm] = vw1.z; Ws[lk + 7][lm] = vw1.w;
        __syncthreads();
        #pragma unroll
        for (int kk = 0; kk < 32; kk++) {
            float4 av = *(const float4*)&As[kk][ty * 4];
            float4 wv = *(const float4*)&Ws[kk][tx * 4];
            float a[4] = {av.x, av.y, av.z, av.w};
            float w[4] = {wv.x, wv.y, wv.z, wv.w};
            #pragma unroll
            for (int mi = 0; mi < 4; mi++)
                #pragma unroll
                for (int ni = 0; ni < 4; ni++)
                    acc[mi][ni] += a[mi] * w[ni];
        }
        __syncthreads();
    }
    #pragma unroll
    for (int mi = 0; mi < 4; mi++) {
        int gm = ty * 4 + mi;
        float scv = alpha * rowscale[(long)b * 64 + gm];
        #pragma unroll
        for (int ni = 0; ni < 4; ni++) {
            float v = scv * acc[mi][ni];
            unsigned short hh, ll; bsplit(v, hh, ll);
            long off = ((long)b * DIM + n0 + tx * 4 + ni) * 128 + hoff + gm;
            ihiT[off] = hh; iloT[off] = ll;
        }
    }
}

// ============ gemm_head: M=64,N=K=512, epi: relu((acc + m*q)/num) ============
__global__ __launch_bounds__(256) void gemm_head(
    const float* __restrict__ A, long sA,
    const float* __restrict__ W,
    float* __restrict__ C, long sC,
    const int* __restrict__ mrow, const float* __restrict__ addvec,
    const float* __restrict__ rownum)
{
    int b = blockIdx.z;
    int n0 = blockIdx.x * 64;
    __shared__ float As[32][68], Ws[32][68];
    float acc[4][4] = {};
    int tx = threadIdx.x & 15, ty = threadIdx.x >> 4;
    int lm = threadIdx.x >> 2, lk = (threadIdx.x & 3) * 8;
    const float* Ab = A + (long)b * sA;
    for (int k0 = 0; k0 < DIM; k0 += 32) {
        const float4* pa = (const float4*)(Ab + (long)lm * DIM + k0 + lk);
        float4 va0 = pa[0], va1 = pa[1];
        const float4* pw = (const float4*)(W + (long)(n0 + lm) * DIM + k0 + lk);
        float4 vw0 = pw[0], vw1 = pw[1];
        As[lk + 0][lm] = va0.x; As[lk + 1][lm] = va0.y; As[lk + 2][lm] = va0.z; As[lk + 3][lm] = va0.w;
        As[lk + 4][lm] = va1.x; As[lk + 5][lm] = va1.y; As[lk + 6][lm] = va1.z; As[lk + 7][lm] = va1.w;
        Ws[lk + 0][lm] = vw0.x; Ws[lk + 1][lm] = vw0.y; Ws[lk + 2][lm] = vw0.z; Ws[lk + 3][lm] = vw0.w;
        Ws[lk + 4][lm] = vw1.x; Ws[lk + 5][lm] = vw1.y; Ws[lk + 6][lm] = vw1.z; Ws[lk + 7][lm] = vw1.w;
        __syncthreads();
        #pragma unroll
        for (int kk = 0; kk < 32; kk++) {
            float4 av = *(const float4*)&As[kk][ty * 4];
            float4 wv = *(const float4*)&Ws[kk][tx * 4];
            float a[4] = {av.x, av.y, av.z, av.w};
            float w[4] = {wv.x, wv.y, wv.z, wv.w};
            #pragma unroll
            for (int mi = 0; mi < 4; mi++)
                #pragma unroll
                for (int ni = 0; ni < 4; ni++)
                    acc[mi][ni] += a[mi] * w[ni];
        }
        __syncthreads();
    }
    #pragma unroll
    for (int mi = 0; mi < 4; mi++) {
        int gm = ty * 4 + mi;
        float mq = (mrow[(long)b * 64 + gm] != 0) ? 1.f : 0.f;
        float inv = 1.f / rownum[(long)b * 64 + gm];
        float4 o;
        float* vo = (float*)&o;
        #pragma unroll
        for (int ni = 0; ni < 4; ni++) {
            float tv = (acc[mi][ni] + mq * addvec[(long)b * DIM + n0 + tx * 4 + ni]) * inv;
            vo[ni] = fmaxf(tv, 0.f);
        }
        *(float4*)(C + (long)b * sC + (long)gm * DIM + n0 + tx * 4) = o;
    }
}

// ============ pre_r/pre_c via MFMA: [rel_rd ; rel_cd] (128x2048) @ dcsum (2048x512) ============
__global__ __launch_bounds__(256) void k_pre_rc_mfma(
    const int* __restrict__ rel_rd, const int* __restrict__ rel_cd,
    const unsigned short* __restrict__ thi, const unsigned short* __restrict__ tlo,
    const int* __restrict__ rm, const int* __restrict__ cm,
    float* __restrict__ pre_r, float* __restrict__ pre_c)
{
    int b = blockIdx.y, n0 = blockIdx.x * 64;
    __shared__ unsigned short Aexp[128 * 64];
    __shared__ unsigned short Bhi[64 * 64], Blo[64 * 64];
    int tid = threadIdx.x, lane = tid & 63, wid = tid >> 6;
    int wm = wid >> 1, wn = wid & 1;
    int arow = tid >> 1, aseg = tid & 1;
    const int* relrow = (arow < 64)
        ? rel_rd + ((long)b * 64 + arow) * ND
        : rel_cd + ((long)b * 64 + arow - 64) * ND;
    int bn = tid >> 2, bq = tid & 3;
    const unsigned short* bsrc_h = thi + ((long)b * DIM + n0 + bn) * ND;
    const unsigned short* bsrc_l = tlo + ((long)b * DIM + n0 + bn) * ND;

    f32x4 acc[4][2];
    #pragma unroll
    for (int i = 0; i < 4; i++)
        #pragma unroll
        for (int j = 0; j < 2; j++)
            acc[i][j] = (f32x4){0.f, 0.f, 0.f, 0.f};

    for (int k0 = 0; k0 < ND; k0 += 64) {
        {
            const int4* pa = (const int4*)(relrow + k0 + aseg * 32);
            #pragma unroll
            for (int p = 0; p < 4; p++) {
                int4 v0 = pa[2 * p], v1 = pa[2 * p + 1];
                uint4 qv;
                qv.x = (v0.x ? 0x3F80u : 0u) | (v0.y ? 0x3F800000u : 0u);
                qv.y = (v0.z ? 0x3F80u : 0u) | (v0.w ? 0x3F800000u : 0u);
                qv.z = (v1.x ? 0x3F80u : 0u) | (v1.y ? 0x3F800000u : 0u);
                qv.w = (v1.z ? 0x3F80u : 0u) | (v1.w ? 0x3F800000u : 0u);
                int c = (aseg * 4 + p) ^ (arow & 7);
                *(uint4*)((char*)Aexp + arow * 128 + c * 16) = qv;
            }
        }
        {
            const uint4* ph = (const uint4*)(bsrc_h + k0 + bq * 16);
            const uint4* pl = (const uint4*)(bsrc_l + k0 + bq * 16);
            #pragma unroll
            for (int s = 0; s < 2; s++) {
                int c = (bq * 2 + s) ^ (bn & 7);
                *(uint4*)((char*)Bhi + bn * 128 + c * 16) = ph[s];
                *(uint4*)((char*)Blo + bn * 128 + c * 16) = pl[s];
            }
        }
        __syncthreads();
        #pragma unroll
        for (int ks = 0; ks < 2; ks++) {
            bf16x8 af[4], bh[2], bl[2];
            #pragma unroll
            for (int i = 0; i < 4; i++) {
                int rr = wm * 64 + i * 16 + (lane & 15);
                int cc = (ks * 4 + (lane >> 4)) ^ (rr & 7);
                af[i] = *(bf16x8*)((char*)Aexp + rr * 128 + cc * 16);
            }
            #pragma unroll
            for (int i = 0; i < 2; i++) {
                int nn = wn * 32 + i * 16 + (lane & 15);
                int c2 = (ks * 4 + (lane >> 4)) ^ (nn & 7);
                bh[i] = *(bf16x8*)((char*)Bhi + nn * 128 + c2 * 16);
                bl[i] = *(bf16x8*)((char*)Blo + nn * 128 + c2 * 16);
            }
            #pragma unroll
            for (int mi = 0; mi < 4; mi++)
                #pragma unroll
                for (int ni = 0; ni < 2; ni++) {
                    acc[mi][ni] = __builtin_amdgcn_mfma_f32_16x16x32_bf16(af[mi], bh[ni], acc[mi][ni], 0, 0, 0);
                    acc[mi][ni] = __builtin_amdgcn_mfma_f32_16x16x32_bf16(af[mi], bl[ni], acc[mi][ni], 0, 0, 0);
                }
        }
        __syncthreads();
    }
    const int* msk = wm ? cm : rm;
    float* outp = wm ? pre_c : pre_r;
    #pragma unroll
    for (int mi = 0; mi < 4; mi++) {
        int grow = mi * 16 + (lane >> 4) * 4;
        #pragma unroll
        for (int ni = 0; ni < 2; ni++) {
            int gcol = n0 + wn * 32 + ni * 16 + (lane & 15);
            #pragma unroll
            for (int r = 0; r < 4; r++) {
                int rrow = grow + r;
                float scv = (msk[b * 64 + rrow] != 0) ? 1.f : 0.f;
                outp[((long)b * 64 + rrow) * DIM + gcol] = scv * acc[mi][ni][r];
            }
        }
    }
}

// ============ projT = Wsr-split @ dcs-split^T via MFMA (prefetched) ============
__global__ __launch_bounds__(256) void k_proj_mfma(
    const unsigned short* __restrict__ whi, const unsigned short* __restrict__ wlo,
    const unsigned short* __restrict__ dhi, const unsigned short* __restrict__ dlo,
    unsigned short* __restrict__ phi, unsigned short* __restrict__ plo)
{
    int flat = blockIdx.x;                   // 1024 blocks
    int tile = (flat & 7) * 128 + (flat >> 3);
    int b = tile >> 6;
    int rem = tile & 63;
    int m0 = (rem >> 4) * 128;
    int n0 = (rem & 15) * 128;

    __shared__ unsigned short Ahi[128 * 64], Alo[128 * 64];
    __shared__ unsigned short Bhi[128 * 64], Blo[128 * 64];

    int tid = threadIdx.x;
    int lane = tid & 63, wid = tid >> 6;
    int wm = wid >> 1, wn = wid & 1;
    int srow = tid >> 1, sseg = tid & 1;

    const unsigned short* sa_h = whi + (long)(m0 + srow) * DIM + sseg * 32;
    const unsigned short* sa_l = wlo + (long)(m0 + srow) * DIM + sseg * 32;
    const unsigned short* sb_h = dhi + ((long)b * ND + n0 + srow) * DIM + sseg * 32;
    const unsigned short* sb_l = dlo + ((long)b * ND + n0 + srow) * DIM + sseg * 32;

    uint4 ra_h[4], ra_l[4], rb_h[4], rb_l[4];
    auto p_load = [&](int t) {
        long ko = (long)t * 64;
        #pragma unroll
        for (int s = 0; s < 4; s++) {
            ra_h[s] = *(const uint4*)(sa_h + ko + s * 8);
            ra_l[s] = *(const uint4*)(sa_l + ko + s * 8);
            rb_h[s] = *(const uint4*)(sb_h + ko + s * 8);
            rb_l[s] = *(const uint4*)(sb_l + ko + s * 8);
        }
    };
    auto p_write = [&]() {
        #pragma unroll
        for (int s = 0; s < 4; s++) {
            int c = (sseg * 4 + s) ^ (srow & 7);
            *(uint4*)((char*)Ahi + srow * 128 + c * 16) = ra_h[s];
            *(uint4*)((char*)Alo + srow * 128 + c * 16) = ra_l[s];
            *(uint4*)((char*)Bhi + srow * 128 + c * 16) = rb_h[s];
            *(uint4*)((char*)Blo + srow * 128 + c * 16) = rb_l[s];
        }
    };

    f32x4 acc[4][4];
    #pragma unroll
    for (int i = 0; i < 4; i++)
        #pragma unroll
        for (int j = 0; j < 4; j++)
            acc[i][j] = (f32x4){0.f, 0.f, 0.f, 0.f};

    p_load(0);
    p_write();
    __syncthreads();
    for (int t = 0; t < 8; t++) {
        if (t < 7) p_load(t + 1);
        #pragma unroll
        for (int ks = 0; ks < 2; ks++) {
            bf16x8 ah[4], al[4], bh[4], bl[4];
            #pragma unroll
            for (int i = 0; i < 4; i++) {
                int rr = wm * 64 + i * 16 + (lane & 15);
                int cc = (ks * 4 + (lane >> 4)) ^ (rr & 7);
                ah[i] = *(bf16x8*)((char*)Ahi + rr * 128 + cc * 16);
                al[i] = *(bf16x8*)((char*)Alo + rr * 128 + cc * 16);
                int nn = wn * 64 + i * 16 + (lane & 15);
                int c2 = (ks * 4 + (lane >> 4)) ^ (nn & 7);
                bh[i] = *(bf16x8*)((char*)Bhi + nn * 128 + c2 * 16);
                bl[i] = *(bf16x8*)((char*)Blo + nn * 128 + c2 * 16);
            }
            #pragma unroll
            for (int mi = 0; mi < 4; mi++)
                #pragma unroll
                for (int ni = 0; ni < 4; ni++) {
                    acc[mi][ni] = __builtin_amdgcn_mfma_f32_16x16x32_bf16(ah[mi], bh[ni], acc[mi][ni], 0, 0, 0);
                    acc[mi][ni] = __builtin_amdgcn_mfma_f32_16x16x32_bf16(ah[mi], bl[ni], acc[mi][ni], 0, 0, 0);
                    acc[mi][ni] = __builtin_amdgcn_mfma_f32_16x16x32_bf16(al[mi], bh[ni], acc[mi][ni], 0, 0, 0);
                }
        }
        __syncthreads();
        if (t < 7) { p_write(); __syncthreads(); }
    }
    #pragma unroll
    for (int mi = 0; mi < 4; mi++) {
        int grow = m0 + wm * 64 + mi * 16 + (lane >> 4) * 4;
        #pragma unroll
        for (int ni = 0; ni < 4; ni++) {
            int gcol = n0 + wn * 64 + ni * 16 + (lane & 15);
            #pragma unroll
            for (int r = 0; r < 4; r++) {
                unsigned short hh, ll; bsplit(acc[mi][ni][r], hh, ll);
                long off = ((long)b * DIM + grow + r) * ND + gcol;
                phi[off] = hh; plo[off] = ll;
            }
        }
    }
}

// ============ final dc: relu((bits @ (phi+plo) + rel^T @ info) / dc_num), prefetched ============
__global__ __launch_bounds__(256) void k_agg_final(
    const unsigned* __restrict__ bits,
    const unsigned short* __restrict__ phi, const unsigned short* __restrict__ plo,
    const unsigned short* __restrict__ ihiT, const unsigned short* __restrict__ iloT,
    const int* __restrict__ rel_rd, const int* __restrict__ rel_cd,
    const int* __restrict__ dmask, const float* __restrict__ rownum,
    float* __restrict__ out)
{
    int flat = blockIdx.x;
    int tile = (flat & 7) * 128 + (flat >> 3);
    int b = tile >> 6;
    int m0 = ((tile >> 2) & 15) * 128;
    int n0 = (tile & 3) * 128;

    __shared__ unsigned short Aexp[128 * 64];
    __shared__ unsigned short Bhi[128 * 64];
    __shared__ unsigned short Blo[128 * 64];
    __shared__ unsigned short dmu[128];

    int tid = threadIdx.x;
    int lane = tid & 63, wid = tid >> 6;
    int wm = wid >> 1, wn = wid & 1;

    if (tid < 128) dmu[tid] = (dmask[(long)b * ND + m0 + tid] != 0) ? 0x3F80 : 0;

    // per-thread staging geometry (fixed across tiles)
    const unsigned short* bsrc[8];
    char* bdst[8];
    int bn_[8], bc_[8];
    #pragma unroll
    for (int u = 0; u < 8; u++) {
        int lin = (u & 3) * 256 + tid;
        int n = lin >> 3, c = lin & 7;
        bn_[u] = n; bc_[u] = c;
        bsrc[u] = (u < 4 ? phi : plo) + ((long)b * DIM + n0 + n) * ND + c * 8;
        bdst[u] = (char*)(u < 4 ? Bhi : Blo) + n * 128 + ((c ^ (n & 7)) * 16);
    }
    int arow = tid >> 1, awsel = tid & 1;
    const unsigned* abit_base = bits + ((long)b * ND + m0 + arow) * 64 + awsel;
    char* adst = (char*)Aexp + arow * 128;

    uint4 rb[8];
    unsigned raw;
    auto b_load = [&](int t) {
        long ko = (long)t * 64;
        #pragma unroll
        for (int u = 0; u < 8; u++) rb[u] = *(const uint4*)(bsrc[u] + ko);
        raw = abit_base[t * 2];
    };
    auto stage_write = [&]() {
        #pragma unroll
        for (int u = 0; u < 8; u++) *(uint4*)(bdst[u]) = rb[u];
        unsigned w = raw;
        #pragma unroll
        for (int c = 0; c < 4; c++) {
            uint4 qv;
            qv.x = (((w >> (c * 8 + 0)) & 1u) ? 0x3F80u : 0u) | (((w >> (c * 8 + 1)) & 1u) ? 0x3F800000u : 0u);
            qv.y = (((w >> (c * 8 + 2)) & 1u) ? 0x3F80u : 0u) | (((w >> (c * 8 + 3)) & 1u) ? 0x3F800000u : 0u);
            qv.z = (((w >> (c * 8 + 4)) & 1u) ? 0x3F80u : 0u) | (((w >> (c * 8 + 5)) & 1u) ? 0x3F800000u : 0u);
            qv.w = (((w >> (c * 8 + 6)) & 1u) ? 0x3F80u : 0u) | (((w >> (c * 8 + 7)) & 1u) ? 0x3F800000u : 0u);
            int chunk = (awsel * 4 + c) ^ (arow & 7);
            *(uint4*)(adst + chunk * 16) = qv;
        }
    };

    f32x4 acc[4][4];
    #pragma unroll
    for (int i = 0; i < 4; i++)
        #pragma unroll
        for (int j = 0; j < 4; j++)
            acc[i][j] = (f32x4){0.f, 0.f, 0.f, 0.f};

    // ---- main loop: 32 K-tiles over graph bits x proj planes ----
    b_load(0);
    stage_write();
    __syncthreads();
    for (int t = 0; t < 32; t++) {
        if (t < 31) b_load(t + 1);
        mfma_phase2(Aexp, Bhi, Blo, wm, wn, lane, acc);
        __syncthreads();
        if (t < 31) { stage_write(); __syncthreads(); }
    }
    // ---- fused header-info tiles: K=128 over rel^T x infoT planes ----
    #pragma unroll
    for (int kt = 0; kt < 2; kt++) {
        #pragma unroll
        for (int u = 0; u < 8; u++) {
            uint4 v = *(const uint4*)((u < 4 ? ihiT : iloT)
                + ((long)b * DIM + n0 + bn_[u]) * 128 + kt * 64 + bc_[u] * 8);
            *(uint4*)(bdst[u]) = v;
        }
        const int* rel = kt ? rel_cd : rel_rd;
        #pragma unroll
        for (int p = 0; p < 8; p++) {
            int lin = p * 256 + tid;
            int h = lin >> 5, q = lin & 31;
            int4 v = *(const int4*)(rel + ((long)b * 64 + h) * ND + m0 + q * 4);
            int cell = q * 4;
            unsigned short e0 = v.x ? dmu[cell + 0] : (unsigned short)0;
            unsigned short e1 = v.y ? dmu[cell + 1] : (unsigned short)0;
            unsigned short e2 = v.z ? dmu[cell + 2] : (unsigned short)0;
            unsigned short e3 = v.w ? dmu[cell + 3] : (unsigned short)0;
            int hc = h >> 3, he = h & 7;
            *(unsigned short*)((char*)Aexp + (cell + 0) * 128 + ((hc ^ ((cell + 0) & 7)) * 16) + he * 2) = e0;
            *(unsigned short*)((char*)Aexp + (cell + 1) * 128 + ((hc ^ ((cell + 1) & 7)) * 16) + he * 2) = e1;
            *(unsigned short*)((char*)Aexp + (cell + 2) * 128 + ((hc ^ ((cell + 2) & 7)) * 16) + he * 2) = e2;
            *(unsigned short*)((char*)Aexp + (cell + 3) * 128 + ((hc ^ ((cell + 3) & 7)) * 16) + he * 2) = e3;
        }
        __syncthreads();
        mfma_phase2(Aexp, Bhi, Blo, wm, wn, lane, acc);
        __syncthreads();
    }
    // ---- epilogue ----
    #pragma unroll
    for (int mi = 0; mi < 4; mi++) {
        int grow = m0 + wm * 64 + mi * 16 + (lane >> 4) * 4;
        float inv[4];
        #pragma unroll
        for (int r = 0; r < 4; r++) inv[r] = 1.f / rownum[(long)b * ND + grow + r];
        #pragma unroll
        for (int ni = 0; ni < 4; ni++) {
            int gcol = n0 + wn * 64 + ni * 16 + (lane & 15);
            #pragma unroll
            for (int r = 0; r < 4; r++) {
                long off = ((long)b * ND + grow + r) * DIM + gcol;
                out[off] = fmaxf(acc[mi][ni][r] * inv[r], 0.f);
            }
        }
    }
}

// ==================================================================================
extern "C" void kernel_launch(void* const* d_in, const int* in_sizes, int n_in,
                              void* d_out, int out_size, void* d_ws, size_t ws_size,
                              hipStream_t stream)
{
    const float* q       = (const float*)d_in[0];
    const float* rh0     = (const float*)d_in[1];
    const float* ch0     = (const float*)d_in[2];
    const float* dc0     = (const float*)d_in[3];
    const int*   rm      = (const int*)d_in[4];
    const int*   cm      = (const int*)d_in[5];
    const int*   dmask   = (const int*)d_in[6];
    const int*   same_row= (const int*)d_in[7];
    const int*   same_col= (const int*)d_in[8];
    const int*   rel_rd  = (const int*)d_in[9];
    const int*   rel_cd  = (const int*)d_in[10];
    const float* wnode   = (const float*)d_in[11];
    const float* w_rdc   = (const float*)d_in[12];
    const float* w_cdc   = (const float*)d_in[13];
    const float* w_dcr   = (const float*)d_in[14];
    const float* w_dcc   = (const float*)d_in[15];
    const float* w_sr    = (const float*)d_in[16];
    const float* w_rq    = (const float*)d_in[18];
    const float* w_cq    = (const float*)d_in[19];

    float* out = (float*)d_out;
    float* rh = out;                           // [16,64,512]
    float* ch = out + (long)NB * NR * DIM;     // [16,64,512]
    float* dc = out + (long)NB * NR * DIM * 2; // [16,2048,512]

    if (ws_size < (size_t)WS_FLOATS * 4) return;

    float* ws      = (float*)d_ws;
    float* rh_num  = ws + OFF_RHNUM;
    float* ch_num  = ws + OFF_CHNUM;
    float* dc_num  = ws + OFF_DCNUM;
    float* rh_w    = ws + OFF_RHW;
    float* ch_w    = ws + OFF_CHW;
    float* qrow    = ws + OFF_QROW;
    float* qcol    = ws + OFF_QCOL;
    float* pre_r   = ws + OFF_PRER;
    float* pre_c   = ws + OFF_PREC;
    unsigned short* ihiT = (unsigned short*)(ws + OFF_INFORC);  // [16][512][128]
    unsigned short* iloT = ihiT + (size_t)NB * DIM * 128;
    unsigned* bits = (unsigned*)(ws + OFF_BITS);
    unsigned short* dhi = (unsigned short*)(ws + OFF_DCS);
    unsigned short* dlo = dhi + (size_t)NB * ND * DIM;
    unsigned short* thi = (unsigned short*)(ws + OFF_PROJ);  // transposed dcs planes
    unsigned short* tlo = thi + (size_t)NB * DIM * ND;
    unsigned short* phi = (unsigned short*)(ws + OFF_PROJ);  // proj planes overwrite thi/tlo (dead)
    unsigned short* plo = phi + (size_t)NB * DIM * ND;
    // whi/wlo in out-dc slice (dead between k_split-read and k_agg_final-write)
    unsigned short* whi = (unsigned short*)dc;
    unsigned short* wlo = whi + (size_t)DIM * DIM;

    hipMemcpyAsync(rh, rh0, sizeof(float) * (size_t)NB * NR * DIM, hipMemcpyDeviceToDevice, stream);
    hipMemcpyAsync(ch, ch0, sizeof(float) * (size_t)NB * NCOL * DIM, hipMemcpyDeviceToDevice, stream);

    k_bits<<<NB * ND, 256, 0, stream>>>(same_row, same_col, dmask, bits, dc_num);
    k_rcnum<<<512, 256, 0, stream>>>(rel_rd, rel_cd, rm, cm, dmask, rh_num, ch_num);
    k_dcnum_final<<<dim3(ND / 256, NB), 256, 0, stream>>>(rel_rd, rel_cd, rm, cm, dmask, dc_num);
    k_q<<<dim3(128, 2, NB), 256, 0, stream>>>(q, w_rq, w_cq, qrow, qcol);

    for (int it = 0; it < 2; it++) {
        k_gate_rc<<<512, 256, 0, stream>>>(rh, ch, rm, cm, wnode, rh_w, ch_w);
        k_split<<<dim3(128, NB), 256, 0, stream>>>(it == 0 ? dc0 : dc, wnode, dmask, dhi, dlo, thi, tlo);
        k_wsplit<<<128, 256, 0, stream>>>(w_sr, whi, wlo);
        // header info projections -> transposed bf16 planes (consumed by fused k_agg_final)
        gemm_info<<<dim3(8, 1, NB), 256, 0, stream>>>(rh, (long)NR * DIM, w_dcr,
            ihiT, iloT, 0, rh_w, 1.0f);
        gemm_info<<<dim3(8, 1, NB), 256, 0, stream>>>(ch, (long)NCOL * DIM, w_dcc,
            ihiT, iloT, 64, ch_w, 2.0f);
        // header pre-aggregations consume thi/tlo ...
        k_pre_rc_mfma<<<dim3(8, NB), 256, 0, stream>>>(rel_rd, rel_cd, thi, tlo, rm, cm, pre_r, pre_c);
        // ... then proj planes overwrite thi/tlo region
        k_proj_mfma<<<1024, 256, 0, stream>>>(whi, wlo, dhi, dlo, phi, plo);
        // header updates
        gemm_head<<<dim3(8, 1, NB), 256, 0, stream>>>(pre_r, (long)NR * DIM, w_rdc,
            rh, (long)NR * DIM, rm, qrow, rh_num);
        gemm_head<<<dim3(8, 1, NB), 256, 0, stream>>>(pre_c, (long)NCOL * DIM, w_cdc,
            ch, (long)NCOL * DIM, cm, qcol, ch_num);
        // final dc update: bits-agg + fused header-info agg, /num, relu
        k_agg_final<<<1024, 256, 0, stream>>>(bits, phi, plo, ihiT, iloT,
            rel_rd, rel_cd, dmask, dc_num, dc);
    }
}

// Round 6
// 1110.972 us; speedup vs baseline: 1.5927x; 1.5927x over previous
//
#include <hip/hip_runtime.h>
#include <math.h>

#define NB 16
#define NR 64
#define NCOL 64
#define ND 2048
#define DIM 512

typedef __attribute__((ext_vector_type(4))) float f32x4;
typedef __attribute__((ext_vector_type(8))) short bf16x8;
typedef __attribute__((ext_vector_type(8))) unsigned short us8;

// ---------------- workspace layout (float offsets) ----------------
#define OFF_RHNUM  0L
#define OFF_CHNUM  1024L
#define OFF_DCNUM  2048L
#define OFF_RHW    34816L
#define OFF_CHW    35840L
#define OFF_QROW   36864L
#define OFF_QCOL   45056L
#define OFF_PRER   53248L
#define OFF_PREC   577536L
#define OFF_INFORC 1101824L   // ihiT/iloT bf16 info planes [b][512][128] (4 MB)
#define OFF_BITS   2150400L
#define OFF_DCS    4247552L   // dhi/dlo row-major planes
#define OFF_PROJ   21024768L  // thi/tlo transposed dcs planes, then phi/plo proj planes
#define WS_FLOATS  37801984L  // 151.2 MB
// whi/wlo live in the out-dc slice (dead mid-iteration)

// RNE fp32 -> bf16 split: v ~= hi + lo, both bf16
__device__ inline void bsplit(float v, unsigned short& h, unsigned short& l) {
    unsigned uv = __float_as_uint(v);
    unsigned hb = (uv + 0x7FFFu + ((uv >> 16) & 1u)) >> 16;
    h = (unsigned short)hb;
    float lo = v - __uint_as_float(hb << 16);
    unsigned lv = __float_as_uint(lo);
    l = (unsigned short)((lv + 0x7FFFu + ((lv >> 16) & 1u)) >> 16);
}

// spread 8 bits to every 4th position of a 32-bit word
__device__ inline unsigned spread4(unsigned x) {
    x = (x | (x << 12)) & 0x000F000Fu;
    x = (x | (x << 6))  & 0x03030303u;
    x = (x | (x << 3))  & 0x11111111u;
    return x;
}

// shared MFMA phase: 2 ks x (4x4) x 2 products (A exact, B hi+lo)
__device__ inline void mfma_phase2(const unsigned short* Aexp, const unsigned short* Bhi,
                                   const unsigned short* Blo, int wm, int wn, int lane,
                                   f32x4 acc[4][4])
{
    #pragma unroll
    for (int ks = 0; ks < 2; ks++) {
        bf16x8 af[4], bh[4], bl[4];
        #pragma unroll
        for (int i = 0; i < 4; i++) {
            int rr = wm * 64 + i * 16 + (lane & 15);
            int cc = (ks * 4 + (lane >> 4)) ^ (rr & 7);
            af[i] = *(const bf16x8*)((const char*)Aexp + rr * 128 + cc * 16);
            int nn = wn * 64 + i * 16 + (lane & 15);
            int c2 = (ks * 4 + (lane >> 4)) ^ (nn & 7);
            bh[i] = *(const bf16x8*)((const char*)Bhi + nn * 128 + c2 * 16);
            bl[i] = *(const bf16x8*)((const char*)Blo + nn * 128 + c2 * 16);
        }
        #pragma unroll
        for (int mi = 0; mi < 4; mi++)
            #pragma unroll
            for (int ni = 0; ni < 4; ni++) {
                acc[mi][ni] = __builtin_amdgcn_mfma_f32_16x16x32_bf16(af[mi], bh[ni], acc[mi][ni], 0, 0, 0);
                acc[mi][ni] = __builtin_amdgcn_mfma_f32_16x16x32_bf16(af[mi], bl[ni], acc[mi][ni], 0, 0, 0);
            }
    }
}

// ============ gate for rh/ch rows ============
__global__ __launch_bounds__(256) void k_gate_rc(
    const float* __restrict__ rh, const float* __restrict__ ch,
    const int* __restrict__ rm, const int* __restrict__ cm,
    const float* __restrict__ wnode,
    float* __restrict__ rh_w, float* __restrict__ ch_w)
{
    int wave = threadIdx.x >> 6, lane = threadIdx.x & 63;
    int idx = blockIdx.x * 4 + wave;   // < 2048
    const float* xrow; float* outw; int mval;
    if (idx < NB * NR) {
        int b = idx >> 6, r = idx & 63;
        xrow = rh + ((long)b * NR + r) * DIM; mval = rm[b * NR + r]; outw = rh_w + b * NR + r;
    } else {
        int tt = idx - NB * NR; int b = tt >> 6, c = tt & 63;
        xrow = ch + ((long)b * NCOL + c) * DIM; mval = cm[b * NCOL + c]; outw = ch_w + b * NCOL + c;
    }
    const float4* px = (const float4*)xrow;
    const float4* pw = (const float4*)wnode;
    float4 xa = px[lane * 2], xb = px[lane * 2 + 1];
    float4 wa = pw[lane * 2], wb = pw[lane * 2 + 1];
    float s = xa.x * wa.x + xa.y * wa.y + xa.z * wa.z + xa.w * wa.w
            + xb.x * wb.x + xb.y * wb.y + xb.z * wb.z + xb.w * wb.w;
    #pragma unroll
    for (int o = 32; o > 0; o >>= 1) s += __shfl_xor(s, o, 64);
    if (lane == 0) {
        float g = 1.f / (1.f + expf(-s));
        *outw = mval ? g : 0.f;
    }
}

// ============ gate+split dc -> dhi/dlo [b][2048][512] AND thi/tlo [b][512][2048] ============
__global__ __launch_bounds__(256) void k_split(
    const float* __restrict__ src, const float* __restrict__ wnode, const int* __restrict__ dmask,
    unsigned short* __restrict__ dhi, unsigned short* __restrict__ dlo,
    unsigned short* __restrict__ thi, unsigned short* __restrict__ tlo)
{
    int b = blockIdx.y, j0 = blockIdx.x * 16;
    __shared__ float X[16 * 512];
    __shared__ float scs[16];
    int t = threadIdx.x;
    int r = t >> 4, u = t & 15;
    const float* row = src + ((long)b * ND + j0 + r) * DIM;
    float part = 0.f;
    #pragma unroll
    for (int i = 0; i < 8; i++) {
        int col = i * 64 + u * 4;
        float4 v = *(const float4*)(row + col);
        float4 w = *(const float4*)(wnode + col);
        part += v.x * w.x + v.y * w.y + v.z * w.z + v.w * w.w;
        *(float4*)&X[r * 512 + (col ^ ((r & 7) * 4))] = v;
    }
    part += __shfl_xor(part, 1, 64);
    part += __shfl_xor(part, 2, 64);
    part += __shfl_xor(part, 4, 64);
    part += __shfl_xor(part, 8, 64);
    if (u == 0) {
        float g = 1.f / (1.f + expf(-part));
        scs[r] = (dmask[(long)b * ND + j0 + r] != 0) ? g : 0.f;
    }
    __syncthreads();
    // row-major planes
    {
        float s = scs[r];
        long ob = ((long)b * ND + j0 + r) * DIM + u * 32;
        #pragma unroll
        for (int g = 0; g < 4; g++) {
            us8 ph, pl;
            #pragma unroll
            for (int e = 0; e < 8; e++) {
                int cc = u * 32 + g * 8 + e;
                float v = X[r * 512 + (cc ^ ((r & 7) * 4))] * s;
                unsigned short hh, ll; bsplit(v, hh, ll);
                ph[e] = hh; pl[e] = ll;
            }
            *(us8*)(dhi + ob + g * 8) = ph;
            *(us8*)(dlo + ob + g * 8) = pl;
        }
    }
    // transposed planes
    #pragma unroll
    for (int h = 0; h < 2; h++) {
        int n = t + h * 256;
        us8 ph0, ph1, pl0, pl1;
        #pragma unroll
        for (int rr = 0; rr < 16; rr++) {
            float v = X[rr * 512 + (n ^ ((rr & 7) * 4))] * scs[rr];
            unsigned short hh, ll; bsplit(v, hh, ll);
            if (rr < 8) { ph0[rr] = hh; pl0[rr] = ll; }
            else        { ph1[rr - 8] = hh; pl1[rr - 8] = ll; }
        }
        long ob = ((long)b * DIM + n) * ND + j0;
        *(us8*)(thi + ob) = ph0; *(us8*)(thi + ob + 8) = ph1;
        *(us8*)(tlo + ob) = pl0; *(us8*)(tlo + ob + 8) = pl1;
    }
}

// ============ split w_sr -> whi/wlo bf16 [512][512] ============
__global__ __launch_bounds__(256) void k_wsplit(
    const float* __restrict__ w, unsigned short* __restrict__ whi, unsigned short* __restrict__ wlo)
{
    long i = ((long)blockIdx.x * 256 + threadIdx.x) * 8;
    float4 a = *(const float4*)(w + i), b4 = *(const float4*)(w + i + 4);
    float v[8] = {a.x, a.y, a.z, a.w, b4.x, b4.y, b4.z, b4.w};
    us8 ph, pl;
    #pragma unroll
    for (int t = 0; t < 8; t++) {
        unsigned short hh, ll; bsplit(v[t], hh, ll);
        ph[t] = hh; pl[t] = ll;
    }
    *(us8*)(whi + i) = ph;
    *(us8*)(wlo + i) = pl;
}

// ============ q projections (once) ============
__global__ __launch_bounds__(256) void k_q(
    const float* __restrict__ q, const float* __restrict__ wrq, const float* __restrict__ wcq,
    float* __restrict__ qrow, float* __restrict__ qcol)
{
    int b = blockIdx.z;
    const float* W = blockIdx.y ? wcq : wrq;
    float* out = blockIdx.y ? qcol : qrow;
    int wave = threadIdx.x >> 6, lane = threadIdx.x & 63;
    int n = blockIdx.x * 4 + wave;
    const float4* qp = (const float4*)(q + (long)b * DIM);
    const float4* wp = (const float4*)(W + (long)n * DIM);
    float4 a0 = qp[lane * 2], a1 = qp[lane * 2 + 1];
    float4 w0 = wp[lane * 2], w1 = wp[lane * 2 + 1];
    float s = a0.x * w0.x + a0.y * w0.y + a0.z * w0.z + a0.w * w0.w
            + a1.x * w1.x + a1.y * w1.y + a1.z * w1.z + a1.w * w1.w;
    #pragma unroll
    for (int o = 32; o > 0; o >>= 1) s += __shfl_xor(s, o, 64);
    if (lane == 0) out[(long)b * DIM + n] = s;
}

// ============ pack same_row bits (vectorized) + partial dc_num ============
__global__ __launch_bounds__(256) void k_bits(
    const int* __restrict__ sr, const int* __restrict__ sc, const int* __restrict__ dmask,
    unsigned* __restrict__ bits, float* __restrict__ dcnum)
{
    long bi = blockIdx.x;                    // = b*ND + i
    int b = (int)(bi >> 11);
    int dmi = dmask[bi];
    int wave = threadIdx.x >> 6, lane = threadIdx.x & 63;
    const int4* sr4 = (const int4*)(sr + bi * ND);
    const int4* sc4 = (const int4*)(sc + bi * ND);
    const int4* dm4 = (const int4*)(dmask + (long)b * ND);
    unsigned* brow = bits + bi * 64;
    int cnt = 0;
    #pragma unroll
    for (int h = 0; h < 2; h++) {
        int vidx = wave * 128 + h * 64 + lane;    // int4 index; j = 4*vidx+k
        int4 vs = sr4[vidx];
        int4 vc = sc4[vidx];
        int4 vd = dm4[vidx];
        bool d0 = dmi && vd.x, d1 = dmi && vd.y, d2 = dmi && vd.z, d3 = dmi && vd.w;
        unsigned long long m0 = __ballot(d0 && vs.x);
        unsigned long long m1 = __ballot(d1 && vs.y);
        unsigned long long m2 = __ballot(d2 && vs.z);
        unsigned long long m3 = __ballot(d3 && vs.w);
        unsigned long long n0 = __ballot(d0 && vc.x);
        unsigned long long n1 = __ballot(d1 && vc.y);
        unsigned long long n2 = __ballot(d2 && vc.z);
        unsigned long long n3 = __ballot(d3 && vc.w);
        cnt += __popcll(m0) + __popcll(m1) + __popcll(m2) + __popcll(m3)
             + __popcll(n0) + __popcll(n1) + __popcll(n2) + __popcll(n3);
        if (lane < 8) {
            unsigned w = spread4((unsigned)(m0 >> (8 * lane)) & 0xFFu)
                       | (spread4((unsigned)(m1 >> (8 * lane)) & 0xFFu) << 1)
                       | (spread4((unsigned)(m2 >> (8 * lane)) & 0xFFu) << 2)
                       | (spread4((unsigned)(m3 >> (8 * lane)) & 0xFFu) << 3);
            brow[wave * 16 + h * 8 + lane] = w;
        }
    }
    __shared__ int red[4];
    if (lane == 0) red[wave] = cnt;
    __syncthreads();
    if (threadIdx.x == 0) dcnum[bi] = (float)(red[0] + red[1] + red[2] + red[3]);
}

// ============ rh_num / ch_num ============
__global__ __launch_bounds__(256) void k_rcnum(
    const int* __restrict__ rel_rd, const int* __restrict__ rel_cd,
    const int* __restrict__ rm, const int* __restrict__ cm, const int* __restrict__ dmask,
    float* __restrict__ rh_num, float* __restrict__ ch_num)
{
    int wave = threadIdx.x >> 6, lane = threadIdx.x & 63;
    long idx = (long)blockIdx.x * 4 + wave;  // < 2048
    const int* row; int mval; float* out; const int* dmb;
    if (idx < NB * NR) {
        int b = (int)(idx >> 6), r = (int)(idx & 63);
        row = rel_rd + ((long)b * NR + r) * ND; mval = rm[b * NR + r];
        out = rh_num + b * NR + r; dmb = dmask + (long)b * ND;
    } else {
        long tt = idx - NB * NR; int b = (int)(tt >> 6), c = (int)(tt & 63);
        row = rel_cd + ((long)b * NCOL + c) * ND; mval = cm[b * NCOL + c];
        out = ch_num + b * NCOL + c; dmb = dmask + (long)b * ND;
    }
    int cnt = 0;
    for (int rr = 0; rr < 32; rr++) {
        int j = rr * 64 + lane;
        cnt += (row[j] != 0 && dmb[j] != 0) ? 1 : 0;
    }
    #pragma unroll
    for (int o = 32; o > 0; o >>= 1) cnt += __shfl_xor(cnt, o, 64);
    if (lane == 0) {
        float s = mval ? (float)cnt : 0.f;
        *out = (s >= 1.f) ? (s + 1.f) : 1.f;
    }
}

// ============ finalize dc_num ============
__global__ __launch_bounds__(256) void k_dcnum_final(
    const int* __restrict__ rel_rd, const int* __restrict__ rel_cd,
    const int* __restrict__ rm, const int* __restrict__ cm, const int* __restrict__ dmask,
    float* __restrict__ dcnum)
{
    int b = blockIdx.y;
    int j = blockIdx.x * 256 + threadIdx.x;
    const int* rd = rel_rd + (long)b * NR * ND;
    const int* cd = rel_cd + (long)b * NCOL * ND;
    const int* rmb = rm + b * NR;
    const int* cmb = cm + b * NCOL;
    int cnt = 0;
    for (int r = 0; r < NR; r++)  cnt += (rd[(long)r * ND + j] != 0 && rmb[r] != 0) ? 1 : 0;
    for (int c = 0; c < NCOL; c++) cnt += (cd[(long)c * ND + j] != 0 && cmb[c] != 0) ? 1 : 0;
    float add = (dmask[(long)b * ND + j] != 0) ? (float)cnt : 0.f;
    float tv = dcnum[(long)b * ND + j] + add;
    dcnum[(long)b * ND + j] = (tv >= 1.f) ? tv : 1.f;
}

// ============ gemm_info: M=64,N=512,K=512 -> transposed bf16 info planes [b][512][128] ============
__global__ __launch_bounds__(256) void gemm_info(
    const float* __restrict__ A, long sA,
    const float* __restrict__ W,
    unsigned short* __restrict__ ihiT, unsigned short* __restrict__ iloT, int hoff,
    const float* __restrict__ rowscale, float alpha)
{
    int b = blockIdx.z;
    int n0 = blockIdx.x * 64;
    __shared__ float As[32][68], Ws[32][68];
    float acc[4][4] = {};
    int tx = threadIdx.x & 15, ty = threadIdx.x >> 4;
    int lm = threadIdx.x >> 2, lk = (threadIdx.x & 3) * 8;
    const float* Ab = A + (long)b * sA;
    for (int k0 = 0; k0 < DIM; k0 += 32) {
        const float4* pa = (const float4*)(Ab + (long)lm * DIM + k0 + lk);
        float4 va0 = pa[0], va1 = pa[1];
        const float4* pw = (const float4*)(W + (long)(n0 + lm) * DIM + k0 + lk);
        float4 vw0 = pw[0], vw1 = pw[1];
        As[lk + 0][lm] = va0.x; As[lk + 1][lm] = va0.y; As[lk + 2][lm] = va0.z; As[lk + 3][lm] = va0.w;
        As[lk + 4][lm] = va1.x; As[lk + 5][lm] = va1.y; As[lk + 6][lm] = va1.z; As[lk + 7][lm] = va1.w;
        Ws[lk + 0][lm] = vw0.x; Ws[lk + 1][lm] = vw0.y; Ws[lk + 2][lm] = vw0.z; Ws[lk + 3][lm] = vw0.w;
        Ws[lk + 4][lm] = vw1.x; Ws[lk + 5][lm] = vw1.y; Ws[lk + 6][lm] = vw1.z; Ws[lk + 7][lm] = vw1.w;
        __syncthreads();
        #pragma unroll
        for (int kk = 0; kk < 32; kk++) {
            float4 av = *(const float4*)&As[kk][ty * 4];
            float4 wv = *(const float4*)&Ws[kk][tx * 4];
            float a[4] = {av.x, av.y, av.z, av.w};
            float w[4] = {wv.x, wv.y, wv.z, wv.w};
            #pragma unroll
            for (int mi = 0; mi < 4; mi++)
                #pragma unroll
                for (int ni = 0; ni < 4; ni++)
                    acc[mi][ni] += a[mi] * w[ni];
        }
        __syncthreads();
    }
    #pragma unroll
    for (int mi = 0; mi < 4; mi++) {
        int gm = ty * 4 + mi;
        float scv = alpha * rowscale[(long)b * 64 + gm];
        #pragma unroll
        for (int ni = 0; ni < 4; ni++) {
            float v = scv * acc[mi][ni];
            unsigned short hh, ll; bsplit(v, hh, ll);
            long off = ((long)b * DIM + n0 + tx * 4 + ni) * 128 + hoff + gm;
            ihiT[off] = hh; iloT[off] = ll;
        }
    }
}

// ============ gemm_head: M=64,N=K=512, epi: relu((acc + m*q)/num) ============
__global__ __launch_bounds__(256) void gemm_head(
    const float* __restrict__ A, long sA,
    const float* __restrict__ W,
    float* __restrict__ C, long sC,
    const int* __restrict__ mrow, const float* __restrict__ addvec,
    const float* __restrict__ rownum)
{
    int b = blockIdx.z;
    int n0 = blockIdx.x * 64;
    __shared__ float As[32][68], Ws[32][68];
    float acc[4][4] = {};
    int tx = threadIdx.x & 15, ty = threadIdx.x >> 4;
    int lm = threadIdx.x >> 2, lk = (threadIdx.x & 3) * 8;
    const float* Ab = A + (long)b * sA;
    for (int k0 = 0; k0 < DIM; k0 += 32) {
        const float4* pa = (const float4*)(Ab + (long)lm * DIM + k0 + lk);
        float4 va0 = pa[0], va1 = pa[1];
        const float4* pw = (const float4*)(W + (long)(n0 + lm) * DIM + k0 + lk);
        float4 vw0 = pw[0], vw1 = pw[1];
        As[lk + 0][lm] = va0.x; As[lk + 1][lm] = va0.y; As[lk + 2][lm] = va0.z; As[lk + 3][lm] = va0.w;
        As[lk + 4][lm] = va1.x; As[lk + 5][lm] = va1.y; As[lk + 6][lm] = va1.z; As[lk + 7][lm] = va1.w;
        Ws[lk + 0][lm] = vw0.x; Ws[lk + 1][lm] = vw0.y; Ws[lk + 2][lm] = vw0.z; Ws[lk + 3][lm] = vw0.w;
        Ws[lk + 4][lm] = vw1.x; Ws[lk + 5][lm] = vw1.y; Ws[lk + 6][lm] = vw1.z; Ws[lk + 7][lm] = vw1.w;
        __syncthreads();
        #pragma unroll
        for (int kk = 0; kk < 32; kk++) {
            float4 av = *(const float4*)&As[kk][ty * 4];
            float4 wv = *(const float4*)&Ws[kk][tx * 4];
            float a[4] = {av.x, av.y, av.z, av.w};
            float w[4] = {wv.x, wv.y, wv.z, wv.w};
            #pragma unroll
            for (int mi = 0; mi < 4; mi++)
                #pragma unroll
                for (int ni = 0; ni < 4; ni++)
                    acc[mi][ni] += a[mi] * w[ni];
        }
        __syncthreads();
    }
    #pragma unroll
    for (int mi = 0; mi < 4; mi++) {
        int gm = ty * 4 + mi;
        float mq = (mrow[(long)b * 64 + gm] != 0) ? 1.f : 0.f;
        float inv = 1.f / rownum[(long)b * 64 + gm];
        float4 o;
        float* vo = (float*)&o;
        #pragma unroll
        for (int ni = 0; ni < 4; ni++) {
            float tv = (acc[mi][ni] + mq * addvec[(long)b * DIM + n0 + tx * 4 + ni]) * inv;
            vo[ni] = fmaxf(tv, 0.f);
        }
        *(float4*)(C + (long)b * sC + (long)gm * DIM + n0 + tx * 4) = o;
    }
}

// ============ pre_r/pre_c via MFMA: [rel_rd ; rel_cd] (128x2048) @ dcsum (2048x512) ============
__global__ __launch_bounds__(256) void k_pre_rc_mfma(
    const int* __restrict__ rel_rd, const int* __restrict__ rel_cd,
    const unsigned short* __restrict__ thi, const unsigned short* __restrict__ tlo,
    const int* __restrict__ rm, const int* __restrict__ cm,
    float* __restrict__ pre_r, float* __restrict__ pre_c)
{
    int b = blockIdx.y, n0 = blockIdx.x * 64;
    __shared__ unsigned short Aexp[128 * 64];
    __shared__ unsigned short Bhi[64 * 64], Blo[64 * 64];
    int tid = threadIdx.x, lane = tid & 63, wid = tid >> 6;
    int wm = wid >> 1, wn = wid & 1;
    int arow = tid >> 1, aseg = tid & 1;
    const int* relrow = (arow < 64)
        ? rel_rd + ((long)b * 64 + arow) * ND
        : rel_cd + ((long)b * 64 + arow - 64) * ND;
    int bn = tid >> 2, bq = tid & 3;
    const unsigned short* bsrc_h = thi + ((long)b * DIM + n0 + bn) * ND;
    const unsigned short* bsrc_l = tlo + ((long)b * DIM + n0 + bn) * ND;

    f32x4 acc[4][2];
    #pragma unroll
    for (int i = 0; i < 4; i++)
        #pragma unroll
        for (int j = 0; j < 2; j++)
            acc[i][j] = (f32x4){0.f, 0.f, 0.f, 0.f};

    for (int k0 = 0; k0 < ND; k0 += 64) {
        {
            const int4* pa = (const int4*)(relrow + k0 + aseg * 32);
            #pragma unroll
            for (int p = 0; p < 4; p++) {
                int4 v0 = pa[2 * p], v1 = pa[2 * p + 1];
                uint4 qv;
                qv.x = (v0.x ? 0x3F80u : 0u) | (v0.y ? 0x3F800000u : 0u);
                qv.y = (v0.z ? 0x3F80u : 0u) | (v0.w ? 0x3F800000u : 0u);
                qv.z = (v1.x ? 0x3F80u : 0u) | (v1.y ? 0x3F800000u : 0u);
                qv.w = (v1.z ? 0x3F80u : 0u) | (v1.w ? 0x3F800000u : 0u);
                int c = (aseg * 4 + p) ^ (arow & 7);
                *(uint4*)((char*)Aexp + arow * 128 + c * 16) = qv;
            }
        }
        {
            const uint4* ph = (const uint4*)(bsrc_h + k0 + bq * 16);
            const uint4* pl = (const uint4*)(bsrc_l + k0 + bq * 16);
            #pragma unroll
            for (int s = 0; s < 2; s++) {
                int c = (bq * 2 + s) ^ (bn & 7);
                *(uint4*)((char*)Bhi + bn * 128 + c * 16) = ph[s];
                *(uint4*)((char*)Blo + bn * 128 + c * 16) = pl[s];
            }
        }
        __syncthreads();
        #pragma unroll
        for (int ks = 0; ks < 2; ks++) {
            bf16x8 af[4], bh[2], bl[2];
            #pragma unroll
            for (int i = 0; i < 4; i++) {
                int rr = wm * 64 + i * 16 + (lane & 15);
                int cc = (ks * 4 + (lane >> 4)) ^ (rr & 7);
                af[i] = *(bf16x8*)((char*)Aexp + rr * 128 + cc * 16);
            }
            #pragma unroll
            for (int i = 0; i < 2; i++) {
                int nn = wn * 32 + i * 16 + (lane & 15);
                int c2 = (ks * 4 + (lane >> 4)) ^ (nn & 7);
                bh[i] = *(bf16x8*)((char*)Bhi + nn * 128 + c2 * 16);
                bl[i] = *(bf16x8*)((char*)Blo + nn * 128 + c2 * 16);
            }
            #pragma unroll
            for (int mi = 0; mi < 4; mi++)
                #pragma unroll
                for (int ni = 0; ni < 2; ni++) {
                    acc[mi][ni] = __builtin_amdgcn_mfma_f32_16x16x32_bf16(af[mi], bh[ni], acc[mi][ni], 0, 0, 0);
                    acc[mi][ni] = __builtin_amdgcn_mfma_f32_16x16x32_bf16(af[mi], bl[ni], acc[mi][ni], 0, 0, 0);
                }
        }
        __syncthreads();
    }
    const int* msk = wm ? cm : rm;
    float* outp = wm ? pre_c : pre_r;
    #pragma unroll
    for (int mi = 0; mi < 4; mi++) {
        int grow = mi * 16 + (lane >> 4) * 4;
        #pragma unroll
        for (int ni = 0; ni < 2; ni++) {
            int gcol = n0 + wn * 32 + ni * 16 + (lane & 15);
            #pragma unroll
            for (int r = 0; r < 4; r++) {
                int rrow = grow + r;
                float scv = (msk[b * 64 + rrow] != 0) ? 1.f : 0.f;
                outp[((long)b * 64 + rrow) * DIM + gcol] = scv * acc[mi][ni][r];
            }
        }
    }
}

// ============ projT = Wsr-split @ dcs-split^T via MFMA -> bf16 hi/lo planes [b][512][2048] ============
__global__ __launch_bounds__(256) void k_proj_mfma(
    const unsigned short* __restrict__ whi, const unsigned short* __restrict__ wlo,
    const unsigned short* __restrict__ dhi, const unsigned short* __restrict__ dlo,
    unsigned short* __restrict__ phi, unsigned short* __restrict__ plo)
{
    int flat = blockIdx.x;                   // 1024 blocks
    int tile = (flat & 7) * 128 + (flat >> 3);
    int b = tile >> 6;
    int rem = tile & 63;
    int m0 = (rem >> 4) * 128;
    int n0 = (rem & 15) * 128;

    __shared__ unsigned short Ahi[128 * 64], Alo[128 * 64];
    __shared__ unsigned short Bhi[128 * 64], Blo[128 * 64];

    int tid = threadIdx.x;
    int lane = tid & 63, wid = tid >> 6;
    int wm = wid >> 1, wn = wid & 1;
    int srow = tid >> 1, sseg = tid & 1;

    f32x4 acc[4][4];
    #pragma unroll
    for (int i = 0; i < 4; i++)
        #pragma unroll
        for (int j = 0; j < 4; j++)
            acc[i][j] = (f32x4){0.f, 0.f, 0.f, 0.f};

    for (int k0 = 0; k0 < DIM; k0 += 64) {
        {
            const uint4* ph = (const uint4*)(whi + (long)(m0 + srow) * DIM + k0 + sseg * 32);
            const uint4* pl = (const uint4*)(wlo + (long)(m0 + srow) * DIM + k0 + sseg * 32);
            #pragma unroll
            for (int s = 0; s < 4; s++) {
                int c = (sseg * 4 + s) ^ (srow & 7);
                *(uint4*)((char*)Ahi + srow * 128 + c * 16) = ph[s];
                *(uint4*)((char*)Alo + srow * 128 + c * 16) = pl[s];
            }
        }
        {
            const uint4* ph = (const uint4*)(dhi + ((long)b * ND + n0 + srow) * DIM + k0 + sseg * 32);
            const uint4* pl = (const uint4*)(dlo + ((long)b * ND + n0 + srow) * DIM + k0 + sseg * 32);
            #pragma unroll
            for (int s = 0; s < 4; s++) {
                int c = (sseg * 4 + s) ^ (srow & 7);
                *(uint4*)((char*)Bhi + srow * 128 + c * 16) = ph[s];
                *(uint4*)((char*)Blo + srow * 128 + c * 16) = pl[s];
            }
        }
        __syncthreads();
        #pragma unroll
        for (int ks = 0; ks < 2; ks++) {
            bf16x8 ah[4], al[4], bh[4], bl[4];
            #pragma unroll
            for (int i = 0; i < 4; i++) {
                int rr = wm * 64 + i * 16 + (lane & 15);
                int cc = (ks * 4 + (lane >> 4)) ^ (rr & 7);
                ah[i] = *(bf16x8*)((char*)Ahi + rr * 128 + cc * 16);
                al[i] = *(bf16x8*)((char*)Alo + rr * 128 + cc * 16);
                int nn = wn * 64 + i * 16 + (lane & 15);
                int c2 = (ks * 4 + (lane >> 4)) ^ (nn & 7);
                bh[i] = *(bf16x8*)((char*)Bhi + nn * 128 + c2 * 16);
                bl[i] = *(bf16x8*)((char*)Blo + nn * 128 + c2 * 16);
            }
            #pragma unroll
            for (int mi = 0; mi < 4; mi++)
                #pragma unroll
                for (int ni = 0; ni < 4; ni++) {
                    acc[mi][ni] = __builtin_amdgcn_mfma_f32_16x16x32_bf16(ah[mi], bh[ni], acc[mi][ni], 0, 0, 0);
                    acc[mi][ni] = __builtin_amdgcn_mfma_f32_16x16x32_bf16(ah[mi], bl[ni], acc[mi][ni], 0, 0, 0);
                    acc[mi][ni] = __builtin_amdgcn_mfma_f32_16x16x32_bf16(al[mi], bh[ni], acc[mi][ni], 0, 0, 0);
                }
        }
        __syncthreads();
    }
    #pragma unroll
    for (int mi = 0; mi < 4; mi++) {
        int grow = m0 + wm * 64 + mi * 16 + (lane >> 4) * 4;
        #pragma unroll
        for (int ni = 0; ni < 4; ni++) {
            int gcol = n0 + wn * 64 + ni * 16 + (lane & 15);
            #pragma unroll
            for (int r = 0; r < 4; r++) {
                unsigned short hh, ll; bsplit(acc[mi][ni][r], hh, ll);
                long off = ((long)b * DIM + grow + r) * ND + gcol;
                phi[off] = hh; plo[off] = ll;
            }
        }
    }
}

// ============ final dc: relu((bits @ (phi+plo) + rel^T @ info) / dc_num) ============
// R4 structure (direct addressing, no prefetch) + 2 fused info K-tiles (ballot transpose)
__global__ __launch_bounds__(256) void k_agg_final(
    const unsigned* __restrict__ bits,
    const unsigned short* __restrict__ phi, const unsigned short* __restrict__ plo,
    const unsigned short* __restrict__ ihiT, const unsigned short* __restrict__ iloT,
    const int* __restrict__ rel_rd, const int* __restrict__ rel_cd,
    const int* __restrict__ dmask, const float* __restrict__ rownum,
    float* __restrict__ out)
{
    int flat = blockIdx.x;
    int tile = (flat & 7) * 128 + (flat >> 3);
    int b = tile >> 6;
    int m0 = ((tile >> 2) & 15) * 128;
    int n0 = (tile & 3) * 128;

    __shared__ unsigned short Aexp[128 * 64];
    __shared__ unsigned short Bhi[128 * 64];
    __shared__ unsigned short Blo[128 * 64];
    __shared__ unsigned short dmu[128];
    __shared__ unsigned LDSw[256];

    int tid = threadIdx.x;
    int lane = tid & 63, wid = tid >> 6;
    int wm = wid >> 1, wn = wid & 1;

    if (tid < 128) dmu[tid] = (dmask[(long)b * ND + m0 + tid] != 0) ? (unsigned short)0x3F80 : (unsigned short)0;

    int arow = tid >> 1, awsel = tid & 1;
    const unsigned* abit_base = bits + ((long)b * ND + m0 + arow) * 64 + awsel;
    char* adst = (char*)Aexp + arow * 128;

    f32x4 acc[4][4];
    #pragma unroll
    for (int i = 0; i < 4; i++)
        #pragma unroll
        for (int j = 0; j < 4; j++)
            acc[i][j] = (f32x4){0.f, 0.f, 0.f, 0.f};

    // ---- main loop: 32 K-tiles over graph bits x proj planes (R4 codepath) ----
    for (int k0 = 0; k0 < ND; k0 += 64) {
        #pragma unroll
        for (int u = 0; u < 8; u++) {
            int lin = (u & 3) * 256 + tid;
            int n = lin >> 3, c = lin & 7;
            const unsigned short* src = (u < 4 ? phi : plo)
                + ((long)b * DIM + n0 + n) * ND + k0 + c * 8;
            uint4 v = *(const uint4*)src;
            char* dst = (char*)(u < 4 ? Bhi : Blo) + n * 128 + ((c ^ (n & 7)) * 16);
            *(uint4*)dst = v;
        }
        {
            unsigned w = abit_base[k0 >> 5];
            #pragma unroll
            for (int c = 0; c < 4; c++) {
                uint4 qv;
                qv.x = (((w >> (c * 8 + 0)) & 1u) ? 0x3F80u : 0u) | (((w >> (c * 8 + 1)) & 1u) ? 0x3F800000u : 0u);
                qv.y = (((w >> (c * 8 + 2)) & 1u) ? 0x3F80u : 0u) | (((w >> (c * 8 + 3)) & 1u) ? 0x3F800000u : 0u);
                qv.z = (((w >> (c * 8 + 4)) & 1u) ? 0x3F80u : 0u) | (((w >> (c * 8 + 5)) & 1u) ? 0x3F800000u : 0u);
                qv.w = (((w >> (c * 8 + 6)) & 1u) ? 0x3F80u : 0u) | (((w >> (c * 8 + 7)) & 1u) ? 0x3F800000u : 0u);
                int chunk = (awsel * 4 + c) ^ (arow & 7);
                *(uint4*)(adst + chunk * 16) = qv;
            }
        }
        __syncthreads();
        mfma_phase2(Aexp, Bhi, Blo, wm, wn, lane, acc);
        __syncthreads();
    }
    // ---- fused header-info tiles: 2 x K=64 over rel^T x infoT planes ----
    #pragma unroll
    for (int kt = 0; kt < 2; kt++) {
        // B: infoT planes, same staging geometry as main loop
        #pragma unroll
        for (int u = 0; u < 8; u++) {
            int lin = (u & 3) * 256 + tid;
            int n = lin >> 3, c = lin & 7;
            uint4 v = *(const uint4*)((u < 4 ? ihiT : iloT)
                + ((long)b * DIM + n0 + n) * 128 + kt * 64 + c * 8);
            char* dst = (char*)(u < 4 ? Bhi : Blo) + n * 128 + ((c ^ (n & 7)) * 16);
            *(uint4*)dst = v;
        }
        // A: transpose rel (h-major) to cell-major bit-words via ballot.
        // lane = h; this wave owns cells m0 + wid*32 .. +31 (each lane reads 128B contiguous)
        const int* relrow = (kt ? rel_cd : rel_rd) + ((long)b * 64 + lane) * ND + m0 + wid * 32;
        #pragma unroll
        for (int c4 = 0; c4 < 32; c4 += 4) {
            int4 v = *(const int4*)(relrow + c4);
            unsigned long long mm;
            mm = __ballot(v.x != 0);
            if ((lane >> 1) == c4 + 0) LDSw[(wid * 32 + c4 + 0) * 2 + (lane & 1)] = (unsigned)(mm >> ((lane & 1) * 32));
            mm = __ballot(v.y != 0);
            if ((lane >> 1) == c4 + 1) LDSw[(wid * 32 + c4 + 1) * 2 + (lane & 1)] = (unsigned)(mm >> ((lane & 1) * 32));
            mm = __ballot(v.z != 0);
            if ((lane >> 1) == c4 + 2) LDSw[(wid * 32 + c4 + 2) * 2 + (lane & 1)] = (unsigned)(mm >> ((lane & 1) * 32));
            mm = __ballot(v.w != 0);
            if ((lane >> 1) == c4 + 3) LDSw[(wid * 32 + c4 + 3) * 2 + (lane & 1)] = (unsigned)(mm >> ((lane & 1) * 32));
        }
        __syncthreads();
        // expansion: identical conflict-free path as main loop, value = dmu[cell]
        {
            unsigned w = LDSw[arow * 2 + awsel];
            unsigned dv = (unsigned)dmu[arow];
            unsigned dvh = dv << 16;
            #pragma unroll
            for (int c = 0; c < 4; c++) {
                uint4 qv;
                qv.x = (((w >> (c * 8 + 0)) & 1u) ? dv : 0u) | (((w >> (c * 8 + 1)) & 1u) ? dvh : 0u);
                qv.y = (((w >> (c * 8 + 2)) & 1u) ? dv : 0u) | (((w >> (c * 8 + 3)) & 1u) ? dvh : 0u);
                qv.z = (((w >> (c * 8 + 4)) & 1u) ? dv : 0u) | (((w >> (c * 8 + 5)) & 1u) ? dvh : 0u);
                qv.w = (((w >> (c * 8 + 6)) & 1u) ? dv : 0u) | (((w >> (c * 8 + 7)) & 1u) ? dvh : 0u);
                int chunk = (awsel * 4 + c) ^ (arow & 7);
                *(uint4*)(adst + chunk * 16) = qv;
            }
        }
        __syncthreads();
        mfma_phase2(Aexp, Bhi, Blo, wm, wn, lane, acc);
        __syncthreads();
    }
    // ---- epilogue ----
    #pragma unroll
    for (int mi = 0; mi < 4; mi++) {
        int grow = m0 + wm * 64 + mi * 16 + (lane >> 4) * 4;
        float inv[4];
        #pragma unroll
        for (int r = 0; r < 4; r++) inv[r] = 1.f / rownum[(long)b * ND + grow + r];
        #pragma unroll
        for (int ni = 0; ni < 4; ni++) {
            int gcol = n0 + wn * 64 + ni * 16 + (lane & 15);
            #pragma unroll
            for (int r = 0; r < 4; r++) {
                long off = ((long)b * ND + grow + r) * DIM + gcol;
                out[off] = fmaxf(acc[mi][ni][r] * inv[r], 0.f);
            }
        }
    }
}

// ==================================================================================
extern "C" void kernel_launch(void* const* d_in, const int* in_sizes, int n_in,
                              void* d_out, int out_size, void* d_ws, size_t ws_size,
                              hipStream_t stream)
{
    const float* q       = (const float*)d_in[0];
    const float* rh0     = (const float*)d_in[1];
    const float* ch0     = (const float*)d_in[2];
    const float* dc0     = (const float*)d_in[3];
    const int*   rm      = (const int*)d_in[4];
    const int*   cm      = (const int*)d_in[5];
    const int*   dmask   = (const int*)d_in[6];
    const int*   same_row= (const int*)d_in[7];
    const int*   same_col= (const int*)d_in[8];
    const int*   rel_rd  = (const int*)d_in[9];
    const int*   rel_cd  = (const int*)d_in[10];
    const float* wnode   = (const float*)d_in[11];
    const float* w_rdc   = (const float*)d_in[12];
    const float* w_cdc   = (const float*)d_in[13];
    const float* w_dcr   = (const float*)d_in[14];
    const float* w_dcc   = (const float*)d_in[15];
    const float* w_sr    = (const float*)d_in[16];
    const float* w_rq    = (const float*)d_in[18];
    const float* w_cq    = (const float*)d_in[19];

    float* out = (float*)d_out;
    float* rh = out;                           // [16,64,512]
    float* ch = out + (long)NB * NR * DIM;     // [16,64,512]
    float* dc = out + (long)NB * NR * DIM * 2; // [16,2048,512]

    if (ws_size < (size_t)WS_FLOATS * 4) return;

    float* ws      = (float*)d_ws;
    float* rh_num  = ws + OFF_RHNUM;
    float* ch_num  = ws + OFF_CHNUM;
    float* dc_num  = ws + OFF_DCNUM;
    float* rh_w    = ws + OFF_RHW;
    float* ch_w    = ws + OFF_CHW;
    float* qrow    = ws + OFF_QROW;
    float* qcol    = ws + OFF_QCOL;
    float* pre_r   = ws + OFF_PRER;
    float* pre_c   = ws + OFF_PREC;
    unsigned short* ihiT = (unsigned short*)(ws + OFF_INFORC);  // [16][512][128]
    unsigned short* iloT = ihiT + (size_t)NB * DIM * 128;
    unsigned* bits = (unsigned*)(ws + OFF_BITS);
    unsigned short* dhi = (unsigned short*)(ws + OFF_DCS);
    unsigned short* dlo = dhi + (size_t)NB * ND * DIM;
    unsigned short* thi = (unsigned short*)(ws + OFF_PROJ);  // transposed dcs planes
    unsigned short* tlo = thi + (size_t)NB * DIM * ND;
    unsigned short* phi = (unsigned short*)(ws + OFF_PROJ);  // proj planes overwrite thi/tlo (dead)
    unsigned short* plo = phi + (size_t)NB * DIM * ND;
    // whi/wlo in out-dc slice (dead between k_split-read and k_agg_final-write)
    unsigned short* whi = (unsigned short*)dc;
    unsigned short* wlo = whi + (size_t)DIM * DIM;

    hipMemcpyAsync(rh, rh0, sizeof(float) * (size_t)NB * NR * DIM, hipMemcpyDeviceToDevice, stream);
    hipMemcpyAsync(ch, ch0, sizeof(float) * (size_t)NB * NCOL * DIM, hipMemcpyDeviceToDevice, stream);

    k_bits<<<NB * ND, 256, 0, stream>>>(same_row, same_col, dmask, bits, dc_num);
    k_rcnum<<<512, 256, 0, stream>>>(rel_rd, rel_cd, rm, cm, dmask, rh_num, ch_num);
    k_dcnum_final<<<dim3(ND / 256, NB), 256, 0, stream>>>(rel_rd, rel_cd, rm, cm, dmask, dc_num);
    k_q<<<dim3(128, 2, NB), 256, 0, stream>>>(q, w_rq, w_cq, qrow, qcol);

    for (int it = 0; it < 2; it++) {
        k_gate_rc<<<512, 256, 0, stream>>>(rh, ch, rm, cm, wnode, rh_w, ch_w);
        k_split<<<dim3(128, NB), 256, 0, stream>>>(it == 0 ? dc0 : dc, wnode, dmask, dhi, dlo, thi, tlo);
        k_wsplit<<<128, 256, 0, stream>>>(w_sr, whi, wlo);
        // header info projections -> transposed bf16 planes (before gemm_head overwrites rh/ch)
        gemm_info<<<dim3(8, 1, NB), 256, 0, stream>>>(rh, (long)NR * DIM, w_dcr,
            ihiT, iloT, 0, rh_w, 1.0f);
        gemm_info<<<dim3(8, 1, NB), 256, 0, stream>>>(ch, (long)NCOL * DIM, w_dcc,
            ihiT, iloT, 64, ch_w, 2.0f);
        // header pre-aggregations consume thi/tlo ...
        k_pre_rc_mfma<<<dim3(8, NB), 256, 0, stream>>>(rel_rd, rel_cd, thi, tlo, rm, cm, pre_r, pre_c);
        // ... then proj planes overwrite thi/tlo region
        k_proj_mfma<<<1024, 256, 0, stream>>>(whi, wlo, dhi, dlo, phi, plo);
        // header updates
        gemm_head<<<dim3(8, 1, NB), 256, 0, stream>>>(pre_r, (long)NR * DIM, w_rdc,
            rh, (long)NR * DIM, rm, qrow, rh_num);
        gemm_head<<<dim3(8, 1, NB), 256, 0, stream>>>(pre_c, (long)NCOL * DIM, w_cdc,
            ch, (long)NCOL * DIM, cm, qcol, ch_num);
        // final dc update: bits-agg + fused header-info agg, /num, relu
        k_agg_final<<<1024, 256, 0, stream>>>(bits, phi, plo, ihiT, iloT,
            rel_rd, rel_cd, dmask, dc_num, dc);
    }
}